// Round 7
// baseline (376.713 us; speedup 1.0000x reference)
//
#include <hip/hip_runtime.h>

// LIF forward recurrence, bit-exact vs the numpy fp32 reference.
//
// Reference per step (exact op order, correctly rounded, no contraction):
//   th   = 1 + 1.5*a
//   v    = (v - v/20) + I_t
//   s    = (v >= th) ? 1 : 0        // STE forward == s_hard exactly (Sterbenz)
//   snum += s                       // exact {0,1} integer cumsum
//   v    = s ? -0.5 : v
//   a    = (a - a/100) + s
//
// R1: LDS 64x64 tile transpose killed 3x HBM write amplification.
// R2: Markstein 3-op constant division (provably == __fdiv_rn for d=20,100).
// R4-R7: producer/consumer waves, barriers, swizzled b128 LDS, quad buffers.
// R8/R9: stateless 2-helper flush: NEUTRAL => helpers have ~3x slack; the
//      compute wave's serial issue stream is the wall clock.
// R10: packed-f32 dual issue, 16 -> 11 arith ops/step. Slice 46 -> 38 us
//      (375.4 total). Issue-stream model validated.
// R11: direct global stores (no LDS): slice 70 us. Store coalescing is
//      load-bearing (scattered 16B/line stores 4x write transactions).
// R12: flush merged into compute wave: slice 45 us. Wait-bearing ops in the
//      compute body stall the whole wave; they must live in helper waves.
// R13: revert to R10; reproduced 376.1 (slice ~38). Architecture confirmed.
// R14 (this): strip the compute wave to its minimum. Compute per-step was
//   ~14.5 issue slots: 5 VOP3P + 6 scalar + pair-assembly movs (VOP3P f32
//   sources are 64-bit pairs, so pk_add forces building {Inext,s}) + oc
//   copy + 0.5 ds_write. Three shaves, all bit-exact:
//   (a) series cumsum back to helper-1 (R7 pattern; R8/R9 proved helper
//       slack): compute drops carry add + oc mov + the whole se ds_write
//       stream; helper-1's serial 128-add/pair chain ~600 cyc fits in its
//       ~3k cyc slack; carry stays in helper-1's registers all row.
//   (b) de-pack the state update: two scalar __fadd_rn writing the x pair
//       halves directly replace pk_add + movs (per-component rn == pk_add).
//   (c) helper-2 is sole flusher: sp at pair-lag 1, se at pair-lag 2
//       (quad buffers; slots disjoint mod 4: compute {2p,2p+1}, helper-1
//       {2p+2,2p+3}, helper-2 se {2p,2p+1} from one pair earlier).
//   Compute -> 11 instr + 0.25 ds_write ~= 11.5 slots/step. Predicted
//   slice 38 -> ~32-34 us. LDS 128 KB, 192 threads, 1 block/CU.

#define LIF_L  2048
#define TILE   64
#define NTILES (LIF_L / TILE)   // 32

typedef float f32x2 __attribute__((ext_vector_type(2)));

// Compile-time, correctly rounded: rn(-0.5/20) and rn(-0.5 - that).
constexpr float kR20 = -0.5f / 20.0f;
constexpr float kC0  = -0.5f - kR20;

__device__ __forceinline__ void barrier_lds_only() {
    asm volatile("s_waitcnt lgkmcnt(0)\n\ts_barrier" ::: "memory");
}

// One step. x = (vn, a): vn = membrane AFTER input add (what the threshold
// sees), a = adaptation. Inext = input of the NEXT step. Returns spike {0,1}.
//
// Bit-exactness vs the proven scalar version:
//   q   = x*C1                    : per-elem rn mul == {__fmul_rn(vn,.05), __fmul_rn(a,.01)}
//   r   = fma(C2,q,x)             : exact remainders {fma(-20,q0,vn), fma(-100,qa,a)}
//   d   = fma(r,C1,q)             : Markstein => d == {__fdiv_rn(vn,20), __fdiv_rn(a,100)}
//   dec = fma(d,-1,x)             : exact product => single-rounded rn(x-d) == __fsub_rn
//   sel = fire ? kC0 : dec.x      : select-before-add (distributes over final rn add)
//   x.x = rn(sel + Inext)         : scalar add into pair low  (== pk_add low)
//   x.y = rn(dec.y + s)           : scalar add into pair high (== pk_add high;
//                                   s in {0,1}, dec.y = ap >= 0)
//   th  = rn(1 + rn(1.5*a'))      : reference order mul-then-add
__device__ __forceinline__ float lif_step(float Inext, f32x2& x, float& th) {
    const f32x2 C1 = {0.05f, 0.01f};
    const f32x2 C2 = {-20.0f, -100.0f};
    const f32x2 M1 = {-1.0f, -1.0f};
    bool fire = (x.x >= th);
    float s = fire ? 1.0f : 0.0f;
    f32x2 q   = x * C1;                              // v_pk_mul_f32
    f32x2 r   = __builtin_elementwise_fma(C2, q, x); // v_pk_fma_f32
    f32x2 d   = __builtin_elementwise_fma(r, C1, q); // v_pk_fma_f32 (exact divs)
    f32x2 dec = __builtin_elementwise_fma(d, M1, x); // v_pk_fma_f32 (= x - d)
    float sel = fire ? kC0 : dec.x;                  // cndmask
    x.x = __fadd_rn(sel, Inext);                     // v_add_f32 -> pair low
    x.y = __fadd_rn(dec.y, s);                       // v_add_f32 -> pair high
    th = __fadd_rn(1.0f, __fmul_rn(1.5f, x.y));      // reference order
    return s;
}

// Swizzled LDS float index for (row, 16B-group g): aligned b128, conflict-free.
__device__ __forceinline__ int sw_idx(int row, int g) {
    return row * 64 + (((g) ^ (row & 15)) << 2);
}

__global__ __launch_bounds__(192, 1) void lif_fwd(const float* __restrict__ I,
                                                  float* __restrict__ spikes,
                                                  float* __restrict__ series) {
    __shared__ float sp_tile[4][64 * 64];      // quad-buffered spike tiles (64 KB)
    __shared__ float se_tile[4][64 * 64];      // quad-buffered series tiles (64 KB)

    const int tid  = threadIdx.x;
    const int wave = tid >> 6;                 // 0 = compute, 1 = cumsum, 2 = flush
    const int lane = tid & 63;
    const int row0 = blockIdx.x * 64;

    const float4* __restrict__ I4 =
        reinterpret_cast<const float4*>(I + (size_t)(row0 + lane) * LIF_L);

    // compute-wave state: x = (vn, a) packed for v_pk_* decay dual issue
    f32x2 x = {0.0f, 0.0f};
    float th = 1.0f;
    float4 bufA[16], bufB[16];
    // helper-1 state: series carry, lane = row, lives here all 2048 steps
    float carry = 0.0f;

    if (wave == 0) {
        #pragma unroll
        for (int i = 0; i < 16; ++i) bufA[i] = I4[i];
        #pragma unroll
        for (int i = 0; i < 16; ++i) bufB[i] = I4[16 + i];
    }

    // Compute: spikes only. 11 VALU + 0.25 ds_write per step.
    auto compute_tile = [&](const float4* buf, float nx0, float* sp) {
        #pragma unroll
        for (int c = 0; c < 16; ++c) {
            float4 in = buf[c];
            float nxt = (c < 15) ? buf[c + 1].x : nx0;
            float4 os;
            os.x = lif_step(in.y, x, th);
            os.y = lif_step(in.z, x, th);
            os.z = lif_step(in.w, x, th);
            os.w = lif_step(nxt,  x, th);
            *reinterpret_cast<float4*>(&sp[sw_idx(lane, c)]) = os;  // ds_write_b128
        }
    };

    // Helper-1: per-row cumsum (lane = row), exact {0,1} adds, b128 LDS ops.
    auto cumsum_tile = [&](const float* sp, float* se) {
        #pragma unroll
        for (int c = 0; c < 16; ++c) {
            int ix = sw_idx(lane, c);
            float4 sv = *reinterpret_cast<const float4*>(&sp[ix]);
            float4 nv;
            carry = __fadd_rn(carry, sv.x); nv.x = carry;
            carry = __fadd_rn(carry, sv.y); nv.y = carry;
            carry = __fadd_rn(carry, sv.z); nv.z = carry;
            carry = __fadd_rn(carry, sv.w); nv.w = carry;
            *reinterpret_cast<float4*>(&se[ix]) = nv;
        }
    };

    // Helper-2: transposed coalesced flush of one stream; instr i = 4 rows x 256 B.
    auto flush_stream = [&](int tkt, const float* buf, float* gbase) {
        const size_t colbase = (size_t)tkt * TILE;
        #pragma unroll
        for (int i = 0; i < 16; ++i) {
            int row = i * 4 + (lane >> 4);
            int g   = lane & 15;
            int ix  = sw_idx(row, g);
            float4 v = *reinterpret_cast<const float4*>(&buf[ix]);
            size_t gaddr = (size_t)(row0 + row) * LIF_L + colbase + (size_t)g * 4;
            *reinterpret_cast<float4*>(gbase + gaddr) = v;
        }
    };

    // init: vn_0 = rn(rn(0 - rn(0/20)) + I_0) = I_0 exactly; a_0 = 0
    if (wave == 0) x.x = bufA[0].x;

    // Pair loop. Pair p: compute -> sp{2p,2p+1}; helper-1 cumsums sp{2p-2,2p-1}
    // -> se (same slots); helper-2 flushes sp{2p-2,2p-1} and se{2p-4,2p-3}.
    // Slot disjointness mod 4: compute writes {2p,2p+1}; helper-1 touches
    // {2p+2,2p+3}; helper-2's se reads {2p,2p+1} were written during pair p-1
    // (one barrier ago). One barrier per pair.
    for (int p = 0; p < NTILES / 2; ++p) {
        const int kt = 2 * p;
        if (wave == 0) {
            compute_tile(bufA, bufB[0].x, sp_tile[kt & 3]);
            if (kt + 2 < NTILES) {
                #pragma unroll
                for (int i = 0; i < 16; ++i) bufA[i] = I4[(kt + 2) * 16 + i];
            }
            float nx0 = (kt + 2 < NTILES) ? bufA[0].x : 0.0f;
            compute_tile(bufB, nx0, sp_tile[(kt + 1) & 3]);
            if (kt + 3 < NTILES) {
                #pragma unroll
                for (int i = 0; i < 16; ++i) bufB[i] = I4[(kt + 3) * 16 + i];
            }
        } else if (wave == 1) {
            if (p > 0) {
                cumsum_tile(sp_tile[(kt - 2) & 3], se_tile[(kt - 2) & 3]);
                cumsum_tile(sp_tile[(kt - 1) & 3], se_tile[(kt - 1) & 3]);
            }
        } else {
            if (p > 0) {
                flush_stream(kt - 2, sp_tile[(kt - 2) & 3], spikes);
                flush_stream(kt - 1, sp_tile[(kt - 1) & 3], spikes);
            }
            if (p > 1) {
                flush_stream(kt - 4, se_tile[(kt - 4) & 3], series);
                flush_stream(kt - 3, se_tile[(kt - 3) & 3], series);
            }
        }
        barrier_lds_only();
    }
    // Tail. Outstanding: cumsum 30,31 (slots 2,3); flush sp 30,31; se 28,29
    // (slots 0,1, written during p=15); then se 30,31 after a barrier.
    if (wave == 1) {
        cumsum_tile(sp_tile[2], se_tile[2]);           // tile 30
        cumsum_tile(sp_tile[3], se_tile[3]);           // tile 31
    } else if (wave == 2) {
        flush_stream(NTILES - 2, sp_tile[2], spikes);
        flush_stream(NTILES - 1, sp_tile[3], spikes);
        flush_stream(NTILES - 4, se_tile[0], series);
        flush_stream(NTILES - 3, se_tile[1], series);
    }
    barrier_lds_only();
    if (wave == 1) {
        flush_stream(NTILES - 2, se_tile[2], series);
    } else if (wave == 2) {
        flush_stream(NTILES - 1, se_tile[3], series);
    }
}

extern "C" void kernel_launch(void* const* d_in, const int* in_sizes, int n_in,
                              void* d_out, int out_size, void* d_ws, size_t ws_size,
                              hipStream_t stream) {
    const float* I = (const float*)d_in[0];
    const int B = in_sizes[0] / LIF_L;                  // 16384
    float* spikes = (float*)d_out;                      // (B, L)
    float* series = (float*)d_out + (size_t)B * LIF_L;  // (B, L)

    const int threads = 192;                            // compute + cumsum + flush
    const int blocks = B / 64;                          // 256 blocks, 64 rows each
    lif_fwd<<<blocks, threads, 0, stream>>>(I, spikes, series);
}